// Round 1
// baseline (465.673 us; speedup 1.0000x reference)
//
#include <hip/hip_runtime.h>

// SSD chunkwise scan: B=4, L=4096, H=16, D=128, CHUNK=64
// Pass 1: per-(b,n,h) intra-chunk scan -> final_h, total_A (workspace)
// Pass 2: inter-chunk sequential scan per (b,h) -> chunk_states (output part 2)
// Pass 3: replay intra-chunk scan fused with Y = h_t + cumA_t @ S (output part 1)

namespace {

constexpr int NB  = 4;
constexpr int NL  = 4096;
constexpr int NH  = 16;
constexpr int ND  = 128;
constexpr int CHK = 64;
constexpr int NCH = NL / CHK;              // 64
constexpr int NTUP = NB * NCH * NH;        // 4096 waves
constexpr long long Y_FLOATS  = (long long)NB * NL * NH * 2 * ND;   // 67,108,864
constexpr int FH_FLOATS = NB * NCH * NH * 2 * ND;                   // 4,194,304
// total_A: NB*NCH*NH*4 floats after final_h in ws

template<bool WRITE_Y>
__global__ __launch_bounds__(256, 4)
void intra_scan(const float* __restrict__ alpha, const float* __restrict__ omega,
                const float* __restrict__ dtp,   const float* __restrict__ K,
                const float* __restrict__ V,     const float* __restrict__ beta,
                const float* __restrict__ rg,
                float* __restrict__ final_h, float* __restrict__ total_A,
                const float* __restrict__ chunk_states, float* __restrict__ Y)
{
    const int wid  = (int)((blockIdx.x * blockDim.x + threadIdx.x) >> 6);
    const int lane = threadIdx.x & 63;
    if (wid >= NTUP) return;
    const int h = wid & (NH - 1);
    const int n = (wid >> 4) & (NCH - 1);
    const int b = wid >> 10;

    const int gi0 = (b * NL + n * CHK) * NH + h;
    const float2* __restrict__ K2 = (const float2*)K;
    const float2* __restrict__ V2 = (const float2*)V;

    // state: lane owns d0=2*lane, d1=2*lane+1 for both s-rows
    float h0x = 0.f, h0y = 0.f, h1x = 0.f, h1y = 0.f;
    // cumulative A (2x2), uniform across lanes
    float C00 = 1.f, C01 = 0.f, C10 = 0.f, C11 = 1.f;

    float S0x = 0.f, S0y = 0.f, S1x = 0.f, S1y = 0.f;
    if constexpr (WRITE_Y) {
        const float2* __restrict__ S2 = (const float2*)chunk_states;
        const int sb = ((b * NCH + n) * NH + h) * 128;  // float2 base (2*128 floats)
        const float2 s0 = S2[sb + lane];
        const float2 s1 = S2[sb + 64 + lane];
        S0x = s0.x; S0y = s0.y; S1x = s1.x; S1y = s1.y;
    }

    #pragma unroll 4
    for (int t = 0; t < CHK; ++t) {
        const int gi = gi0 + t * NH;
        const float a   = alpha[gi];
        const float w   = omega[gi];
        const float dtv = dtp[gi];
        const float be  = beta[gi];
        const float r   = rg[gi];
        const float2 vv = V2[gi];
        const float2 kk = K2[((size_t)gi << 6) + lane];

        // --- build A_bar (Cayley + eigenvalue gating) ---
        const float tau  = 0.5f * dtv;
        const float ta   = tau * a;
        const float to   = tau * w;
        const float opta = 1.f + ta, omta = 1.f - ta;
        const float to2  = to * to;
        const float den  = opta * opta + to2 + 1e-6f;
        const float inv  = 1.f / den;
        const float a11  = (opta * omta - to2) * inv;
        const float a12  = (2.f * to) * inv;
        const float numer = omta * omta + to2;
        const float eig   = numer * inv;                       // numer / (denom_e + 1e-6)
        const float ex    = 4.f * r - 0.5f;                    // (8*r - 1) * 0.5
        const float sc    = exp2f(ex * log2f(fmaxf(eig, 1e-8f)));
        const float A00 = a11 * sc, A01 = a12 * sc;
        const float A10 = -(a12 * sc), A11v = a11 * sc;

        // --- kTh = h . k (reduce over d across the wave) ---
        float p0 = h0x * kk.x + h0y * kk.y;
        float p1 = h1x * kk.x + h1y * kk.y;
        #pragma unroll
        for (int m = 1; m < 64; m <<= 1) {
            p0 += __shfl_xor(p0, m, 64);
            p1 += __shfl_xor(p1, m, 64);
        }

        // --- selective erasure + 2x2 rotate + write term ---
        const float bk0 = be * p0, bk1 = be * p1;
        const float hm0x = h0x - bk0 * kk.x, hm0y = h0y - bk0 * kk.y;
        const float hm1x = h1x - bk1 * kk.x, hm1y = h1y - bk1 * kk.y;
        const float bdt = be * dtv;
        const float sv0 = bdt * vv.x, sv1 = bdt * vv.y;
        h0x = A00 * hm0x + A01 * hm1x + sv0 * kk.x;
        h0y = A00 * hm0y + A01 * hm1y + sv0 * kk.y;
        h1x = A10 * hm0x + A11v * hm1x + sv1 * kk.x;
        h1y = A10 * hm0y + A11v * hm1y + sv1 * kk.y;

        // --- cumA = A @ cumA ---
        const float c00 = A00 * C00 + A01 * C10;
        const float c01 = A00 * C01 + A01 * C11;
        const float c10 = A10 * C00 + A11v * C10;
        const float c11 = A10 * C01 + A11v * C11;
        C00 = c00; C01 = c01; C10 = c10; C11 = c11;

        if constexpr (WRITE_Y) {
            // Y[t] = h_t + cumA_t @ S   (layout (B,L,H,2,D))
            float2* __restrict__ Y2 = (float2*)Y;
            const int yb = gi << 7;  // gi*256 floats -> gi*128 float2
            float2 y0, y1;
            y0.x = h0x + c00 * S0x + c01 * S1x;
            y0.y = h0y + c00 * S0y + c01 * S1y;
            y1.x = h1x + c10 * S0x + c11 * S1x;
            y1.y = h1y + c10 * S0y + c11 * S1y;
            Y2[yb + lane]      = y0;   // s=0, d=2l..2l+1
            Y2[yb + 64 + lane] = y1;   // s=1
        }
    }

    if constexpr (!WRITE_Y) {
        float2* __restrict__ FH2 = (float2*)final_h;
        const int fb = wid * 128;            // (b,n,h) row-major, 2*128 floats each
        FH2[fb + lane]      = make_float2(h0x, h0y);
        FH2[fb + 64 + lane] = make_float2(h1x, h1y);
        if (lane == 0) {
            ((float4*)total_A)[wid] = make_float4(C00, C01, C10, C11);
        }
    }
}

__global__ __launch_bounds__(128)
void inter_scan(const float* __restrict__ final_h, const float* __restrict__ total_A,
                float* __restrict__ states_out)
{
    const int bh = blockIdx.x;          // 0..63 = b*16 + h
    const int b = bh >> 4, h = bh & 15;
    const int d = threadIdx.x;          // 0..127
    float s0 = 0.f, s1 = 0.f;
    #pragma unroll 8
    for (int nn = 0; nn < NCH; ++nn) {
        const int tup  = (b * NCH + nn) * NH + h;
        const int base = tup * 256 + d;
        states_out[base]       = s0;    // emit state ENTERING chunk nn
        states_out[base + 128] = s1;
        const float4 A  = ((const float4*)total_A)[tup];
        const float f0  = final_h[base];
        const float f1  = final_h[base + 128];
        const float ns0 = A.x * s0 + A.y * s1 + f0;
        const float ns1 = A.z * s0 + A.w * s1 + f1;
        s0 = ns0; s1 = ns1;
    }
}

} // namespace

extern "C" void kernel_launch(void* const* d_in, const int* in_sizes, int n_in,
                              void* d_out, int out_size, void* d_ws, size_t ws_size,
                              hipStream_t stream)
{
    const float* alpha = (const float*)d_in[0];
    const float* omega = (const float*)d_in[1];
    const float* dtp   = (const float*)d_in[2];
    const float* K     = (const float*)d_in[3];
    const float* V     = (const float*)d_in[4];
    const float* beta  = (const float*)d_in[5];
    const float* rg    = (const float*)d_in[6];

    float* Y       = (float*)d_out;
    float* states  = Y + Y_FLOATS;            // chunk_states output (B,NC,H,2,D)
    float* final_h = (float*)d_ws;
    float* total_A = final_h + FH_FLOATS;

    const dim3 blk(256);
    const dim3 grid(NTUP / 4);                // 1024 blocks, 4 waves each

    intra_scan<false><<<grid, blk, 0, stream>>>(alpha, omega, dtp, K, V, beta, rg,
                                                final_h, total_A, nullptr, nullptr);
    inter_scan<<<dim3(NB * NH), dim3(128), 0, stream>>>(final_h, total_A, states);
    intra_scan<true><<<grid, blk, 0, stream>>>(alpha, omega, dtp, K, V, beta, rg,
                                               nullptr, nullptr, states, Y);
}

// Round 2
// 443.882 us; speedup vs baseline: 1.0491x; 1.0491x over previous
//
#include <hip/hip_runtime.h>

// SSD chunkwise scan: B=4, L=4096, H=16, D=128, CHUNK=64
// Pass 1: per-(b,n,h) intra-chunk scan -> final_h, total_A (workspace)
// Pass 2: inter-chunk sequential scan per (b,h) -> chunk_states (output part 2)
// Pass 3: replay intra-chunk scan fused with Y = h_t + cumA_t @ S (output part 1)
//
// v2: lane-parallel A_bar precompute (+readlane broadcast), DPP-based wave
//     reduce (4x row_ror + ds_swizzle xor16 + shfl xor32), h-update refactored
//     to h = A*h + c*k so the reduce feeds only a 3-FMA tail, depth-4 K
//     prefetch, pass2 software-pipelined (LDS A + depth-8 f prefetch).

namespace {

constexpr int NB  = 4;
constexpr int NL  = 4096;
constexpr int NH  = 16;
constexpr int CHK = 64;
constexpr int NCH = NL / CHK;              // 64
constexpr int NTUP = NB * NCH * NH;        // 4096 waves
constexpr long long Y_FLOATS  = (long long)NB * NL * NH * 2 * 128;  // 67,108,864
constexpr int FH_FLOATS = NB * NCH * NH * 2 * 128;                  // 4,194,304

__device__ __forceinline__ float rl(float x, int l) {
    return __int_as_float(__builtin_amdgcn_readlane(__float_as_int(x), l));
}

template<int CTRL>
__device__ __forceinline__ float dpp_add(float x) {
    int y = __builtin_amdgcn_update_dpp(0, __float_as_int(x), CTRL, 0xF, 0xF, false);
    return x + __int_as_float(y);
}

// full 64-lane sum, result in every lane
__device__ __forceinline__ float wave_allsum(float x) {
    x = dpp_add<0x121>(x);   // row_ror:1
    x = dpp_add<0x122>(x);   // row_ror:2
    x = dpp_add<0x124>(x);   // row_ror:4
    x = dpp_add<0x128>(x);   // row_ror:8  -> every lane has its 16-row sum
    x += __int_as_float(__builtin_amdgcn_ds_swizzle(__float_as_int(x), 0x401F)); // xor16
    x += __shfl_xor(x, 32, 64);                                                  // xor32
    return x;
}

template<bool WRITE_Y>
__global__ __launch_bounds__(256, 4)
void intra_scan(const float* __restrict__ alpha, const float* __restrict__ omega,
                const float* __restrict__ dtp,   const float* __restrict__ K,
                const float* __restrict__ V,     const float* __restrict__ beta,
                const float* __restrict__ rg,
                float* __restrict__ final_h, float* __restrict__ total_A,
                const float* __restrict__ chunk_states, float* __restrict__ Y)
{
    const int wid  = (int)((blockIdx.x * blockDim.x + threadIdx.x) >> 6);
    const int lane = threadIdx.x & 63;
    const int h = wid & (NH - 1);
    const int n = (wid >> 4) & (NCH - 1);
    const int b = wid >> 10;

    const int gi0 = (b * NL + n * CHK) * NH + h;
    const float2* __restrict__ K2 = (const float2*)K;
    const float2* __restrict__ V2 = (const float2*)V;

    // ---- per-lane precompute: lane t owns step t's scalars ----
    {
        // nothing; scope below
    }
    const int gl = gi0 + lane * NH;
    const float a   = alpha[gl];
    const float w   = omega[gl];
    const float dtv = dtp[gl];
    const float be  = beta[gl];
    const float r   = rg[gl];
    const float2 vv = V2[gl];

    const float tau  = 0.5f * dtv;
    const float ta   = tau * a;
    const float to   = tau * w;
    const float opta = 1.f + ta, omta = 1.f - ta;
    const float to2  = to * to;
    const float den  = opta * opta + to2 + 1e-6f;
    const float inv  = 1.f / den;
    const float a11  = (opta * omta - to2) * inv;
    const float a12  = (2.f * to) * inv;
    const float eig  = (omta * omta + to2) * inv;
    const float ex   = 4.f * r - 0.5f;
    const float sc   = exp2f(ex * log2f(fmaxf(eig, 1e-8f)));
    const float A00L = a11 * sc;
    const float A01L = a12 * sc;
    const float eb0L = be * A00L;
    const float eb1L = be * A01L;
    const float bdt  = be * dtv;
    const float sv0L = bdt * vv.x;
    const float sv1L = bdt * vv.y;

    // ---- chunk entry state (pass 3 only) ----
    float S0x = 0.f, S0y = 0.f, S1x = 0.f, S1y = 0.f;
    if constexpr (WRITE_Y) {
        const float2* __restrict__ S2 = (const float2*)chunk_states;
        const int sb = ((b * NCH + n) * NH + h) * 128;
        const float2 s0 = S2[sb + lane];
        const float2 s1 = S2[sb + 64 + lane];
        S0x = s0.x; S0y = s0.y; S1x = s1.x; S1y = s1.y;
    }

    const float2* __restrict__ kp = K2 + (((size_t)gi0) << 6) + lane;
    float2* __restrict__ yp = nullptr;
    if constexpr (WRITE_Y) yp = ((float2*)Y) + (((size_t)gi0) << 7) + lane;

    // state: lane owns d0=2*lane, d1=2*lane+1 for both s-rows
    float h0x = 0.f, h0y = 0.f, h1x = 0.f, h1y = 0.f;
    float C00 = 1.f, C01 = 0.f, C10 = 0.f, C11 = 1.f;

    float2 cur[4], nxt[4];
    #pragma unroll
    for (int j = 0; j < 4; ++j) cur[j] = kp[j * 1024];

    for (int g = 0; g < 16; ++g) {
        if (g < 15) {
            #pragma unroll
            for (int j = 0; j < 4; ++j) nxt[j] = kp[(g * 4 + 4 + j) * 1024];
        }
        #pragma unroll
        for (int j = 0; j < 4; ++j) {
            const int t = g * 4 + j;
            const float2 kk = cur[j];

            // broadcast step-t scalars from lane t (uniform, off critical path)
            const float A00 = rl(A00L, t);
            const float A01 = rl(A01L, t);
            const float eb0 = rl(eb0L, t);
            const float eb1 = rl(eb1L, t);
            const float sv0 = rl(sv0L, t);
            const float sv1 = rl(sv1L, t);

            // retrieval p = h . k (wave reduce) -- the only serial dependence
            float p0 = h0x * kk.x + h0y * kk.y;
            float p1 = h1x * kk.x + h1y * kk.y;
            p0 = wave_allsum(p0);
            p1 = wave_allsum(p1);

            // rotation (independent of reduce, overlaps it)
            const float R0x = A00 * h0x + A01 * h1x;
            const float R0y = A00 * h0y + A01 * h1y;
            const float R1x = A00 * h1x - A01 * h0x;
            const float R1y = A00 * h1y - A01 * h0y;

            // c = sv - be * (A @ p)
            const float c0 = sv0 - (eb0 * p0 + eb1 * p1);
            const float c1 = sv1 - (eb0 * p1 - eb1 * p0);

            h0x = R0x + c0 * kk.x;  h0y = R0y + c0 * kk.y;
            h1x = R1x + c1 * kk.x;  h1y = R1y + c1 * kk.y;

            // cumA = A @ cumA (uniform)
            const float nc00 = A00 * C00 + A01 * C10;
            const float nc01 = A00 * C01 + A01 * C11;
            const float nc10 = A00 * C10 - A01 * C00;
            const float nc11 = A00 * C11 - A01 * C01;
            C00 = nc00; C01 = nc01; C10 = nc10; C11 = nc11;

            if constexpr (WRITE_Y) {
                float2 y0, y1;
                y0.x = h0x + C00 * S0x + C01 * S1x;
                y0.y = h0y + C00 * S0y + C01 * S1y;
                y1.x = h1x + C10 * S0x + C11 * S1x;
                y1.y = h1y + C10 * S0y + C11 * S1y;
                yp[t * 2048]      = y0;   // s=0, d=2l..2l+1
                yp[t * 2048 + 64] = y1;   // s=1
            }
        }
        #pragma unroll
        for (int j = 0; j < 4; ++j) cur[j] = nxt[j];
    }

    if constexpr (!WRITE_Y) {
        float2* __restrict__ FH2 = (float2*)final_h;
        const int fb = wid * 128;
        FH2[fb + lane]      = make_float2(h0x, h0y);
        FH2[fb + 64 + lane] = make_float2(h1x, h1y);
        if (lane == 0) {
            ((float4*)total_A)[wid] = make_float4(C00, C01, C10, C11);
        }
    }
}

__global__ __launch_bounds__(128)
void inter_scan(const float* __restrict__ final_h, const float* __restrict__ total_A,
                float* __restrict__ states_out)
{
    const int bh = blockIdx.x;          // 0..63 = b*16 + h
    const int b = bh >> 4, h = bh & 15;
    const int d = threadIdx.x;          // 0..127

    __shared__ float4 As[NCH];
    if (d < NCH) As[d] = ((const float4*)total_A)[(b * NCH + d) * NH + h];
    __syncthreads();

    // depth-8 software pipeline on final_h loads
    float fa[8], fb[8];
    #pragma unroll
    for (int j = 0; j < 8; ++j) {
        const int base = ((b * NCH + j) * NH + h) * 256 + d;
        fa[j] = final_h[base];
        fb[j] = final_h[base + 128];
    }

    float s0 = 0.f, s1 = 0.f;
    #pragma unroll 8
    for (int nn = 0; nn < NCH; ++nn) {
        const int slot = nn & 7;        // static after unroll 8
        const int base = ((b * NCH + nn) * NH + h) * 256 + d;
        states_out[base]       = s0;    // state ENTERING chunk nn
        states_out[base + 128] = s1;
        const float4 A = As[nn];
        const float n0 = A.x * s0 + A.y * s1 + fa[slot];
        const float n1 = A.z * s0 + A.w * s1 + fb[slot];
        s0 = n0; s1 = n1;
        if (nn < NCH - 8) {
            const int nb = ((b * NCH + nn + 8) * NH + h) * 256 + d;
            fa[slot] = final_h[nb];
            fb[slot] = final_h[nb + 128];
        }
    }
}

} // namespace

extern "C" void kernel_launch(void* const* d_in, const int* in_sizes, int n_in,
                              void* d_out, int out_size, void* d_ws, size_t ws_size,
                              hipStream_t stream)
{
    const float* alpha = (const float*)d_in[0];
    const float* omega = (const float*)d_in[1];
    const float* dtp   = (const float*)d_in[2];
    const float* K     = (const float*)d_in[3];
    const float* V     = (const float*)d_in[4];
    const float* beta  = (const float*)d_in[5];
    const float* rg    = (const float*)d_in[6];

    float* Y       = (float*)d_out;
    float* states  = Y + Y_FLOATS;            // chunk_states output (B,NC,H,2,D)
    float* final_h = (float*)d_ws;
    float* total_A = final_h + FH_FLOATS;

    const dim3 blk(256);
    const dim3 grid(NTUP / 4);                // 1024 blocks, 4 waves each

    intra_scan<false><<<grid, blk, 0, stream>>>(alpha, omega, dtp, K, V, beta, rg,
                                                final_h, total_A, nullptr, nullptr);
    inter_scan<<<dim3(NB * NH), dim3(128), 0, stream>>>(final_h, total_A, states);
    intra_scan<true><<<grid, blk, 0, stream>>>(alpha, omega, dtp, K, V, beta, rg,
                                               nullptr, nullptr, states, Y);
}